// Round 10
// baseline (227.936 us; speedup 1.0000x reference)
//
#include <hip/hip_runtime.h>
#include <cstdint>
#include <cstddef>

typedef unsigned int u32;
typedef unsigned long long u64;

#define NB 8192
#define BIMG 2
#define WPR (NB / 64)   // 128 u64 words per mask row

// ---------------- workspace layout (bytes) ----------------
#define WS_KCOUNT 0
#define WS_KEYS   256
#define WS_BOXES  (WS_KEYS + BIMG * NB * 8)          // 131328
#define WS_PROB   (WS_BOXES + BIMG * NB * 16)        // 393472
#define WS_SBOXES (WS_PROB + BIMG * NB * 4)          // 459008
#define WS_SPROB  (WS_SBOXES + BIMG * NB * 16)       // 721152
#define WS_REMV   (WS_SPROB + BIMG * NB * 4)         // 786688 (unused in fast path)
#define WS_MASK   (WS_REMV + BIMG * WPR * 8 + 256)   // 788992 (pad)
#define WS_ROWNZ  (WS_MASK + (size_t)BIMG * NB * WPR * 8)
#define WS_DIAG   (WS_ROWNZ + (size_t)BIMG * NB)         // 8-aligned (BIMG*NB=16384)
#define WS_DIAG2  (WS_DIAG + (size_t)BIMG * NB * 8)
#define WS_NEEDED (WS_DIAG2 + (size_t)BIMG * NB * 8)     // ~17.9 MB

// ---------------------------------------------------------------------------
// Kernel 1: sigmoid + box decode + sort-key build (NO atomics)
// ---------------------------------------------------------------------------
__global__ void decode_kernel(const float* __restrict__ offsets,
                              const float* __restrict__ labels,
                              const float* __restrict__ anchors,
                              u64* __restrict__ keys,
                              float4* __restrict__ boxes,
                              float* __restrict__ prob) {
  int idx = blockIdx.x * blockDim.x + threadIdx.x;
  if (idx >= BIMG * NB) return;
  int n = idx & (NB - 1);

  float logit = labels[idx];
  float p = 1.0f / (1.0f + expf(-logit));
  bool valid = p > 0.5f;

  const float4 an = ((const float4*)anchors)[n];   // x1,y1,x2,y2
  float acx = (an.x + an.z) / 2.0f;
  float acy = (an.y + an.w) / 2.0f;
  float aw = an.z - an.x;
  float ah = an.w - an.y;

  const float4 of = ((const float4*)offsets)[idx]; // gcx,gcy,gw,gh
  float cx = of.x * aw / 10.0f + acx;
  float cy = of.y * ah / 10.0f + acy;
  float w = expf(of.z / 5.0f) * aw;
  float h = expf(of.w / 5.0f) * ah;

  float4 bx;
  bx.x = cx - w / 2.0f;
  bx.y = cy - h / 2.0f;
  bx.z = cx + w / 2.0f;
  bx.w = cy + h / 2.0f;
  boxes[idx] = bx;
  prob[idx] = p;

  u32 e = valid ? (__float_as_uint(p) ^ 0x80000000u) : 0u;
  keys[idx] = ((u64)e << 32) | (u32)(~(u32)n);
}

// ---------------------------------------------------------------------------
// Kernel 2: per-image bitonic sort (desc) + valid count + fused sorted gather
// ---------------------------------------------------------------------------
__global__ __launch_bounds__(1024) void sort_kernel(u64* __restrict__ keys,
                                                    const float4* __restrict__ boxes,
                                                    const float* __restrict__ prob,
                                                    float4* __restrict__ sboxes,
                                                    float* __restrict__ sprob,
                                                    u32* __restrict__ kcount) {
  __shared__ u64 s[NB];                 // 64 KB
  __shared__ u32 scnt;
  const int b = blockIdx.x;
  u64* kb = keys + (size_t)b * NB;
  if (threadIdx.x == 0) scnt = 0;
  u32 lc = 0;
  for (int i = threadIdx.x; i < NB; i += 1024) {
    u64 k = kb[i];
    s[i] = k;
    lc += ((u32)(k >> 32) != 0u) ? 1u : 0u;
  }
  // wave reduction of local valid count
  for (int off = 32; off > 0; off >>= 1) lc += __shfl_down(lc, off, 64);
  __syncthreads();                       // scnt init + s[] loaded
  if ((threadIdx.x & 63) == 0) atomicAdd(&scnt, lc);   // 16 LDS atomics
  __syncthreads();
  if (threadIdx.x == 0) kcount[b] = scnt;

  for (int k = 2; k <= NB; k <<= 1) {
    for (int j = k >> 1; j > 0; j >>= 1) {
      for (int p = threadIdx.x; p < NB / 2; p += 1024) {
        int i = ((p & ~(j - 1)) << 1) | (p & (j - 1));
        int ixj = i | j;
        u64 a = s[i];
        u64 c = s[ixj];
        bool desc = (i & k) == 0;
        if ((a < c) == desc) { s[i] = c; s[ixj] = a; }
      }
      __syncthreads();
    }
  }

  // write back keys + fused gather into sorted order
  const float4* bx = boxes + (size_t)b * NB;
  const float* pb = prob + (size_t)b * NB;
  for (int i = threadIdx.x; i < NB; i += 1024) {
    u64 k = s[i];
    kb[i] = k;
    u32 oi = (u32)(~k);                 // original anchor index
    sboxes[(size_t)b * NB + i] = bx[oi];
    sprob[(size_t)b * NB + i]  = pb[oi];
  }
}

// ---------------------------------------------------------------------------
// Kernel 4: overlap bitmask build + per-row nonzero flag + CONTIGUOUS
// diagonal-band arrays:  diag[i] = mask[i][i>>6],  diag2[i] = mask[i][i>>6+1]
// (diag2 only needed for even-chunk rows; rows of chunk 127 never use it).
// ---------------------------------------------------------------------------
__global__ __launch_bounds__(256) void mask_kernel(const float4* __restrict__ sboxes,
                                                   const u32* __restrict__ kcount,
                                                   u64* __restrict__ mask,
                                                   unsigned char* __restrict__ rownz,
                                                   u64* __restrict__ diag,
                                                   u64* __restrict__ diag2) {
  const int i = blockIdx.x;       // sorted row
  const int b = blockIdx.y;
  const int K = (int)kcount[b];
  if (i >= K) return;
  const int wave = threadIdx.x >> 6;
  const int lane = threadIdx.x & 63;
  const int tc = i >> 6;
  __shared__ u32 anyf[4];
  const float4* sb = sboxes + (size_t)b * NB;
  const float4 bi = sb[i];
  const float area_i = (bi.z - bi.x) * (bi.w - bi.y);
  u64* mrow = mask + ((size_t)b * NB + i) * WPR;
  bool any = false;
  for (int pass = 0; pass < WPR / 4; ++pass) {
    int w = pass * 4 + wave;
    u64 word = 0;
    bool act = ((w + 1) * 64 > i) && (w * 64 < K);   // uniform per wave
    if (act) {
      int j = w * 64 + lane;
      float4 bj = sb[j];
      float lx = fmaxf(bi.x, bj.x);
      float ly = fmaxf(bi.y, bj.y);
      float rx = fminf(bi.z, bj.z);
      float ry = fminf(bi.w, bj.w);
      float iw = fmaxf(rx - lx, 0.0f);
      float ih = fmaxf(ry - ly, 0.0f);
      float inter = iw * ih;
      float area_j = (bj.z - bj.x) * (bj.w - bj.y);
      float iou = inter / (area_i + area_j - inter);
      bool pred = (j > i) && (j < K) && (iou > 0.5f);
      word = __ballot(pred);
      any = any || (word != 0ull);
    }
    if (lane == 0) {
      if (act) mrow[w] = word;
      if (w == tc)      diag[(size_t)b * NB + i]  = word;
      else if (w == tc + 1) diag2[(size_t)b * NB + i] = word;   // 0 if !act
    }
  }
  if (lane == 0) anyf[wave] = any ? 1u : 0u;
  __syncthreads();
  if (threadIdx.x == 0) {
    u32 a = anyf[0] | anyf[1] | anyf[2] | anyf[3];
    rownz[(size_t)b * NB + i] = (unsigned char)(a ? 1 : 0);
  }
}

// ---------------------------------------------------------------------------
// Kernel 5: PAIRED chunked greedy scan + fused output. 8 waves / image.
// Stage t handles chunks A=2t, B=2t+1 (32 stages, 2 barriers each).
// Wave 0: coalesced prefetch (diag/diag2/rownz bands) one stage ahead;
//   merge slot words; resolve A; cross-inject A->B (shfl-OR of diag2 over
//   kept A rows); resolve B; publish rcA/rcB/kuA/kuB.
// Waves 1-7: speculative full-row loads for nz rows of both chunks (masked
//   by ku in phase 2), accumulate into per-wave remv (lane l owns words l,
//   l+64), post words 2t+2, 2t+3 from cumulative accumulators.
// ---------------------------------------------------------------------------
#define SCAN_WAVES 8
#define MAXROWS 10                 // 10-bit nz-window per row wave covers 64 bits

__device__ inline u64 rdl64(u64 v, int lane) {
  u32 lo = (u32)__builtin_amdgcn_readlane((int)(u32)v, lane);
  u32 hi = (u32)__builtin_amdgcn_readlane((int)(u32)(v >> 32), lane);
  return ((u64)hi << 32) | lo;
}

__device__ inline u64 shflxor64(u64 v, int off) {
  u32 lo = (u32)v, hi = (u32)(v >> 32);
  lo = (u32)__shfl_xor((int)lo, off, 64);
  hi = (u32)__shfl_xor((int)hi, off, 64);
  return ((u64)hi << 32) | lo;
}

__device__ inline void resolve_diag(u64& rc, u64 dw) {
  u64 nzd = __ballot(dw != 0ull) & ~rc;
  while (nzd) {
    int tt = __builtin_ctzll(nzd);
    rc |= rdl64(dw, tt);
    nzd &= ~(1ull << tt) & ~rc;
  }
}

__global__ __launch_bounds__(512) void scan_kernel(const u64* __restrict__ mask,
                                                   const u64* __restrict__ diag,
                                                   const u64* __restrict__ diag2,
                                                   const unsigned char* __restrict__ rownz,
                                                   const u32* __restrict__ kcount,
                                                   const float4* __restrict__ sboxes,
                                                   const float* __restrict__ sprob,
                                                   float* __restrict__ out) {
  __shared__ u64 s_remv[WPR];               // finalized rc words (1 KB)
  __shared__ u64 s_slotE[2][SCAN_WAVES];    // posts of word 2t+2
  __shared__ u64 s_slotO[2][SCAN_WAVES];    // posts of word 2t+3
  __shared__ u64 s_kuA, s_kuB, s_nzwA, s_nzwB;
  const int b = blockIdx.x;
  const int tid = threadIdx.x;
  const int w = tid >> 6;                   // wave id 0..7
  const int l = tid & 63;
  const int K = (int)kcount[b];
  const u64* mb = mask + (size_t)b * NB * WPR;
  const u64* dg = diag + (size_t)b * NB;
  const u64* dg2 = diag2 + (size_t)b * NB;
  const unsigned char* nzb = rownz + (size_t)b * NB;
  const int NC = min(WPR, (K + 63) >> 6);
  const int NCL = min(NC, 64);
  const int NP = (NC + 1) >> 1;             // chunk pairs

  if (tid < 2 * SCAN_WAVES) { ((u64*)s_slotE)[tid] = 0; ((u64*)s_slotO)[tid] = 0; }

  // per-wave accumulators: lane l owns words l (plo) and l+64 (phi)
  u64 plo = 0, phi = 0;
  const bool okLo = (l < NCL);              // lo word l is mask-written
  const bool okHi = (64 + l) < NC;          // hi word exists (K > 4096)
  u64 LA[MAXROWS], HA[MAXROWS], LB[MAXROWS], HB[MAXROWS];
  u64 bqA[MAXROWS], bqB[MAXROWS];
  // wave-0 pipeline regs
  u64 dwA = 0, dwB = 0, cw = 0;
  unsigned char nzcA = 0, nzcB = 0;

  if (w == 0 && NP > 0) {
    int rA = l, rB = 64 + l;
    dwA = (rA < K) ? dg[rA] : 0ull;
    dwB = (rB < K) ? dg[rB] : 0ull;
    cw  = (rA < K) ? dg2[rA] : 0ull;
    nzcA = (rA < K) ? nzb[rA] : (unsigned char)0;
    nzcB = (rB < K) ? nzb[rB] : (unsigned char)0;
    u64 a0 = __ballot(nzcA != 0), b0 = __ballot(nzcB != 0);
    if (l == 0) { s_nzwA = a0; s_nzwB = b0; }
  }
  __syncthreads();

  for (int t = 0; t < NP; ++t) {
    const int cA = 2 * t, cB = 2 * t + 1;
    const bool hasB = (cB < NC);
    // ---------------- phase 1 ----------------
    if (w == 0) {
      // coalesced prefetch of next pair's bands
      u64 dwA_n = 0, dwB_n = 0, cw_n = 0;
      unsigned char nzA_n = 0, nzB_n = 0;
      if (t + 1 < NP) {
        int rA = (t + 1) * 128 + l, rB = (t + 1) * 128 + 64 + l;
        dwA_n = (rA < K) ? dg[rA] : 0ull;
        dwB_n = (rB < K) ? dg[rB] : 0ull;
        cw_n  = (rA < K) ? dg2[rA] : 0ull;
        nzA_n = (rA < K) ? nzb[rA] : (unsigned char)0;
        nzB_n = (rB < K) ? nzb[rB] : (unsigned char)0;
      }
      // merge slot posts from stage t-1 (parity (t+1)&1)
      int pr = (t + 1) & 1;
      u64 valA = s_slotE[pr][l & (SCAN_WAVES - 1)];
      u64 valB = s_slotO[pr][l & (SCAN_WAVES - 1)];
#pragma unroll
      for (int off = 1; off < SCAN_WAVES; off <<= 1) {
        valA |= shflxor64(valA, off);
        valB |= shflxor64(valB, off);
      }
      // ---- chunk A ----
      int loA = cA * 64;
      u64 tailA = (loA + 64 <= K) ? 0ull : ((~0ull) << (K - loA));
      u64 rcA = valA | tailA;
      u64 nzwA = __ballot(nzcA != 0);
      resolve_diag(rcA, dwA);
      u64 kuA = (~rcA) & nzwA;
      // ---- cross-inject A -> B: OR diag2 over kept A rows ----
      u64 m = ((~rcA >> l) & 1ull) ? cw : 0ull;
#pragma unroll
      for (int off = 32; off > 0; off >>= 1) m |= shflxor64(m, off);
      // ---- chunk B ----
      u64 rcB = ~0ull, kuB = 0;
      if (hasB) {
        int loB = cB * 64;
        u64 tailB = (loB + 64 <= K) ? 0ull : ((~0ull) << (K - loB));
        rcB = valB | tailB | m;
        u64 nzwB = __ballot(nzcB != 0);
        resolve_diag(rcB, dwB);
        kuB = (~rcB) & nzwB;
      }
      if (l == 0) {
        s_remv[cA] = rcA;
        if (hasB) s_remv[cB] = rcB;
        s_kuA = kuA; s_kuB = kuB;
      }
      dwA = dwA_n; dwB = dwB_n; cw = cw_n; nzcA = nzA_n; nzcB = nzB_n;
    } else {
      // speculative full-row loads for nz rows of chunks A and B
      u64 kkA = (s_nzwA >> ((w - 1) * MAXROWS)) & ((1ull << MAXROWS) - 1ull);
      u64 kkB = (s_nzwB >> ((w - 1) * MAXROWS)) & ((1ull << MAXROWS) - 1ull);
#pragma unroll
      for (int q = 0; q < MAXROWS; ++q) {
        bool hA = (kkA != 0ull);
        int tA = hA ? __builtin_ctzll(kkA) : 0;
        if (hA) kkA &= kkA - 1;
        bqA[q] = hA ? (1ull << ((w - 1) * MAXROWS + tA)) : 0ull;
        LA[q] = 0; HA[q] = 0;
        if (hA) {
          const u64* rp = mb + (size_t)(cA * 64 + (w - 1) * MAXROWS + tA) * WPR;
          if (okLo) LA[q] = rp[l];
          if (okHi) HA[q] = rp[64 + l];
        }
        bool hB = (kkB != 0ull);
        int tB = hB ? __builtin_ctzll(kkB) : 0;
        if (hB) kkB &= kkB - 1;
        bqB[q] = hB ? (1ull << ((w - 1) * MAXROWS + tB)) : 0ull;
        LB[q] = 0; HB[q] = 0;
        if (hB) {
          const u64* rp = mb + (size_t)(cB * 64 + (w - 1) * MAXROWS + tB) * WPR;
          if (okLo) LB[q] = rp[l];
          if (okHi) HB[q] = rp[64 + l];
        }
      }
    }
    __syncthreads();                     // barrier A: rc/ku published, loads drained

    // ---------------- phase 2 (register/LDS only) ----------------
    if (w == 0) {
      u64 a1 = __ballot(nzcA != 0), b1 = __ballot(nzcB != 0);  // next pair's nz
      if (l == 0) { s_nzwA = a1; s_nzwB = b1; }
    } else {
      u64 kuA = s_kuA, kuB = s_kuB;
#pragma unroll
      for (int q = 0; q < MAXROWS; ++q) {
        if (kuA & bqA[q]) { plo |= LA[q]; phi |= HA[q]; }
        if (kuB & bqB[q]) { plo |= LB[q]; phi |= HB[q]; }
      }
      int wE = cA + 2, wO = cA + 3;
      u64 vE = (wE < 64) ? plo : phi;
      if (l == (wE & 63)) s_slotE[t & 1][w] = vE;
      u64 vO = (wO < 64) ? plo : phi;
      if (l == (wO & 63)) s_slotO[t & 1][w] = vO;
    }
    __syncthreads();                     // barrier B: posts/nzw settled
  }

  // ---------------- fused output ----------------
  const float4* sbx = sboxes + (size_t)b * NB;
  const float* spb = sprob + (size_t)b * NB;
  for (int p = tid; p < NB; p += 512) {
    bool kp = false;
    if (p < K) {
      u64 wv = s_remv[p >> 6];
      kp = !((wv >> (p & 63)) & 1ull);
    }
    float4 bv = sbx[p];
    if (!kp) { bv.x = 0.0f; bv.y = 0.0f; bv.z = 0.0f; bv.w = 0.0f; }
    ((float4*)out)[(size_t)b * NB + p] = bv;
    out[(size_t)BIMG * NB * 4 + (size_t)b * NB + p] = kp ? spb[p] : 0.0f;
    out[(size_t)BIMG * NB * 5 + (size_t)b * NB + p] = kp ? 1.0f : 0.0f;
  }
}

// ---------------------------------------------------------------------------
// Fallback NMS kernel (used only if workspace is too small)
// ---------------------------------------------------------------------------
__global__ __launch_bounds__(1024) void nms_kernel(const u64* __restrict__ keys,
                                                   const float4* __restrict__ boxes,
                                                   const float* __restrict__ prob,
                                                   const u32* __restrict__ kcount,
                                                   float* __restrict__ out) {
  __shared__ float4 sb[NB];
  __shared__ unsigned char flag[NB];
  const int b = blockIdx.x;
  const int t = threadIdx.x;
  const u64* kb = keys + (size_t)b * NB;
  const float4* bx = boxes + (size_t)b * NB;
  const int K = (int)kcount[b];

  for (int p = t; p < NB; p += 1024) {
    u32 idx = (u32)(~kb[p]);
    sb[p] = bx[idx];
    flag[p] = (p < K) ? (unsigned char)0 : (unsigned char)1;
  }
  __syncthreads();

  for (int i = 0; i < K; ++i) {
    if (flag[i]) continue;
    float4 bi = sb[i];
    float area_i = (bi.z - bi.x) * (bi.w - bi.y);
    for (int j = i + 1 + t; j < K; j += 1024) {
      float4 bj = sb[j];
      float lx = fmaxf(bi.x, bj.x);
      float ly = fmaxf(bi.y, bj.y);
      float rx = fminf(bi.z, bj.z);
      float ry = fminf(bi.w, bj.w);
      float iw = fmaxf(rx - lx, 0.0f);
      float ih = fmaxf(ry - ly, 0.0f);
      float inter = iw * ih;
      float area_j = (bj.z - bj.x) * (bj.w - bj.y);
      float iou = inter / (area_i + area_j - inter);
      if (iou > 0.5f) flag[j] = (unsigned char)1;
    }
    __syncthreads();
  }

  float4* oboxes = (float4*)(out) + (size_t)b * NB;
  float* oscores = out + (size_t)BIMG * NB * 4 + (size_t)b * NB;
  float* okeep   = out + (size_t)BIMG * NB * 5 + (size_t)b * NB;
  const float* pb = prob + (size_t)b * NB;
  for (int p = t; p < NB; p += 1024) {
    bool kp = (p < K) && (flag[p] == 0);
    float4 bv = sb[p];
    if (!kp) { bv.x = 0.0f; bv.y = 0.0f; bv.z = 0.0f; bv.w = 0.0f; }
    oboxes[p] = bv;
    u32 idx = (u32)(~kb[p]);
    oscores[p] = kp ? pb[idx] : 0.0f;
    okeep[p] = kp ? 1.0f : 0.0f;
  }
}

// ---------------------------------------------------------------------------
extern "C" void kernel_launch(void* const* d_in, const int* in_sizes, int n_in,
                              void* d_out, int out_size, void* d_ws, size_t ws_size,
                              hipStream_t stream) {
  const float* offsets = (const float*)d_in[0];   // [B,N,4] f32
  const float* labels  = (const float*)d_in[1];   // [B,N,1] f32
  const float* anchors = (const float*)d_in[2];   // [N,4]   f32
  float* out = (float*)d_out;

  char* ws = (char*)d_ws;
  u32*    kcount = (u32*)(ws + WS_KCOUNT);
  u64*    keys   = (u64*)(ws + WS_KEYS);
  float4* boxes  = (float4*)(ws + WS_BOXES);
  float*  prob   = (float*)(ws + WS_PROB);
  float4* sboxes = (float4*)(ws + WS_SBOXES);
  float*  sprob  = (float*)(ws + WS_SPROB);

  int total = BIMG * NB;
  decode_kernel<<<(total + 255) / 256, 256, 0, stream>>>(
      offsets, labels, anchors, keys, boxes, prob);

  sort_kernel<<<BIMG, 1024, 0, stream>>>(keys, boxes, prob, sboxes, sprob, kcount);

  if (ws_size >= WS_NEEDED) {
    u64*    mask   = (u64*)(ws + WS_MASK);
    unsigned char* rownz = (unsigned char*)(ws + WS_ROWNZ);
    u64*    diag   = (u64*)(ws + WS_DIAG);
    u64*    diag2  = (u64*)(ws + WS_DIAG2);

    mask_kernel<<<dim3(NB, BIMG), 256, 0, stream>>>(sboxes, kcount, mask, rownz,
                                                    diag, diag2);

    scan_kernel<<<BIMG, 512, 0, stream>>>(mask, diag, diag2, rownz, kcount,
                                          sboxes, sprob, out);
  } else {
    nms_kernel<<<BIMG, 1024, 0, stream>>>(keys, boxes, prob, kcount, out);
  }
}

// Round 11
// 216.268 us; speedup vs baseline: 1.0540x; 1.0540x over previous
//
#include <hip/hip_runtime.h>
#include <cstdint>
#include <cstddef>

typedef unsigned int u32;
typedef unsigned long long u64;

#define NB 8192
#define BIMG 2
#define WPR (NB / 64)   // 128 u64 words per mask row

// ---------------- workspace layout (bytes) ----------------
#define WS_KCOUNT 0
#define WS_KEYS   256                                // (unused, kept for layout)
#define WS_BOXES  (WS_KEYS + BIMG * NB * 8)          // 131328
#define WS_PROB   (WS_BOXES + BIMG * NB * 16)        // 393472
#define WS_SBOXES (WS_PROB + BIMG * NB * 4)          // 459008
#define WS_SPROB  (WS_SBOXES + BIMG * NB * 16)       // 721152
#define WS_REMV   (WS_SPROB + BIMG * NB * 4)         // 786688 (unused in fast path)
#define WS_MASK   (WS_REMV + BIMG * WPR * 8 + 256)   // 788992 (pad)
#define WS_ROWNZ  (WS_MASK + (size_t)BIMG * NB * WPR * 8)
#define WS_DIAG   (WS_ROWNZ + (size_t)BIMG * NB)         // 8-aligned (BIMG*NB=16384)
#define WS_DIAG2  (WS_DIAG + (size_t)BIMG * NB * 8)
#define WS_NEEDED (WS_DIAG2 + (size_t)BIMG * NB * 8)     // ~17.9 MB

__device__ inline u64 rdl64(u64 v, int lane) {
  u32 lo = (u32)__builtin_amdgcn_readlane((int)(u32)v, lane);
  u32 hi = (u32)__builtin_amdgcn_readlane((int)(u32)(v >> 32), lane);
  return ((u64)hi << 32) | lo;
}

__device__ inline u64 shflxor64(u64 v, int off) {
  u32 lo = (u32)v, hi = (u32)(v >> 32);
  lo = (u32)__shfl_xor((int)lo, off, 64);
  hi = (u32)__shfl_xor((int)hi, off, 64);
  return ((u64)hi << 32) | lo;
}

// ---------------------------------------------------------------------------
// Kernel 2 (fused decode + sort + gather): one 1024-thread block per image.
// Decode all 8192 anchors (coalesced, staged via LDS), then hybrid bitonic:
//   j<=4  : in-register (8 elems/thread, contiguous)
//   8<=j<=256 : wave-internal shfl_xor (m=j/8), no barrier
//   j>=512    : LDS + barrier (only 10 of 91 phases)
// Then valid count + coalesced sorted gather of boxes/prob.
// ---------------------------------------------------------------------------
__global__ __launch_bounds__(1024) void sort_kernel(const float* __restrict__ offsets,
                                                    const float* __restrict__ labels,
                                                    const float* __restrict__ anchors,
                                                    float4* __restrict__ boxes,
                                                    float* __restrict__ prob,
                                                    float4* __restrict__ sboxes,
                                                    float* __restrict__ sprob,
                                                    u32* __restrict__ kcount) {
  __shared__ u64 s[NB];                 // 64 KB
  __shared__ u32 scnt;
  const int b = blockIdx.x;
  const int tid = threadIdx.x;
  if (tid == 0) scnt = 0;

  // ---- fused decode (coalesced): element n = q*1024 + tid ----
  u32 lc = 0;
  for (int q = 0; q < 8; ++q) {
    int n = (q << 10) + tid;
    int idx = b * NB + n;
    float logit = labels[idx];
    float p = 1.0f / (1.0f + expf(-logit));
    bool valid = p > 0.5f;

    const float4 an = ((const float4*)anchors)[n];   // x1,y1,x2,y2
    float acx = (an.x + an.z) / 2.0f;
    float acy = (an.y + an.w) / 2.0f;
    float aw = an.z - an.x;
    float ah = an.w - an.y;

    const float4 of = ((const float4*)offsets)[idx]; // gcx,gcy,gw,gh
    float cx = of.x * aw / 10.0f + acx;
    float cy = of.y * ah / 10.0f + acy;
    float w = expf(of.z / 5.0f) * aw;
    float h = expf(of.w / 5.0f) * ah;

    float4 bx;
    bx.x = cx - w / 2.0f;
    bx.y = cy - h / 2.0f;
    bx.z = cx + w / 2.0f;
    bx.w = cy + h / 2.0f;
    boxes[idx] = bx;
    prob[idx] = p;

    u32 e32 = valid ? (__float_as_uint(p) ^ 0x80000000u) : 0u;
    s[n] = ((u64)e32 << 32) | (u32)(~(u32)n);
    lc += valid ? 1u : 0u;
  }
  for (int off = 32; off > 0; off >>= 1) lc += __shfl_down(lc, off, 64);
  __syncthreads();                       // scnt init + s[] filled
  if ((tid & 63) == 0) atomicAdd(&scnt, lc);
  __syncthreads();
  if (tid == 0) kcount[b] = scnt;

  // ---- registers: thread t owns elements t*8 .. t*8+7 ----
  u64 e[8];
#pragma unroll
  for (int r = 0; r < 8; ++r) e[r] = s[tid * 8 + r];

  for (int k = 2; k <= NB; k <<= 1) {
    int j = k >> 1;
    if (j >= 512) {
      // dump to LDS (own slots), run LDS phases, read back
#pragma unroll
      for (int r = 0; r < 8; ++r) s[tid * 8 + r] = e[r];
      __syncthreads();
      for (; j >= 512; j >>= 1) {
        for (int p = tid; p < NB / 2; p += 1024) {
          int i = ((p & ~(j - 1)) << 1) | (p & (j - 1));
          int ixj = i | j;
          u64 a = s[i];
          u64 c = s[ixj];
          bool desc = (i & k) == 0;
          if ((a < c) == desc) { s[i] = c; s[ixj] = a; }
        }
        __syncthreads();
      }
#pragma unroll
      for (int r = 0; r < 8; ++r) e[r] = s[tid * 8 + r];
      // no barrier needed: each thread only reads/writes its own slots next
    }
    // shfl phases: partner thread = tid ^ (j/8), same wave (m <= 32)
    for (; j >= 8; j >>= 1) {
      int m = j >> 3;
      bool lowSide = (tid & m) == 0;
      bool descT = ((tid * 8) & k) == 0;   // uniform over r (k >= 16 here)
      bool takeMax = (lowSide == descT);
#pragma unroll
      for (int r = 0; r < 8; ++r) {
        u64 p = shflxor64(e[r], m);
        bool sel = (e[r] < p) == takeMax;  // keys unique -> never equal
        e[r] = sel ? p : e[r];
      }
    }
    // register phases: j in {4,2,1}
    for (; j >= 1; j >>= 1) {
#pragma unroll
      for (int r = 0; r < 8; ++r) {
        if ((r & j) == 0) {
          int i = tid * 8 + r;
          bool desc = (i & k) == 0;
          u64 a = e[r];
          u64 c = e[r | j];
          if ((a < c) == desc) { e[r] = c; e[r | j] = a; }
        }
      }
    }
  }

  // ---- dump sorted keys, coalesced gather ----
#pragma unroll
  for (int r = 0; r < 8; ++r) s[tid * 8 + r] = e[r];
  __syncthreads();
  for (int q = 0; q < 8; ++q) {
    int i = (q << 10) + tid;
    u64 kk = s[i];
    u32 oi = (u32)(~kk);
    sboxes[(size_t)b * NB + i] = boxes[(size_t)b * NB + oi];
    sprob[(size_t)b * NB + i]  = prob[(size_t)b * NB + oi];
  }
}

// ---------------------------------------------------------------------------
// Kernel 4: overlap bitmask build + per-row nonzero flag + CONTIGUOUS
// diagonal-band arrays:  diag[i] = mask[i][i>>6],  diag2[i] = mask[i][i>>6+1]
// ---------------------------------------------------------------------------
__global__ __launch_bounds__(256) void mask_kernel(const float4* __restrict__ sboxes,
                                                   const u32* __restrict__ kcount,
                                                   u64* __restrict__ mask,
                                                   unsigned char* __restrict__ rownz,
                                                   u64* __restrict__ diag,
                                                   u64* __restrict__ diag2) {
  const int i = blockIdx.x;       // sorted row
  const int b = blockIdx.y;
  const int K = (int)kcount[b];
  if (i >= K) return;
  const int wave = threadIdx.x >> 6;
  const int lane = threadIdx.x & 63;
  const int tc = i >> 6;
  __shared__ u32 anyf[4];
  const float4* sb = sboxes + (size_t)b * NB;
  const float4 bi = sb[i];
  const float area_i = (bi.z - bi.x) * (bi.w - bi.y);
  u64* mrow = mask + ((size_t)b * NB + i) * WPR;
  bool any = false;
  for (int pass = 0; pass < WPR / 4; ++pass) {
    int w = pass * 4 + wave;
    u64 word = 0;
    bool act = ((w + 1) * 64 > i) && (w * 64 < K);   // uniform per wave
    if (act) {
      int j = w * 64 + lane;
      float4 bj = sb[j];
      float lx = fmaxf(bi.x, bj.x);
      float ly = fmaxf(bi.y, bj.y);
      float rx = fminf(bi.z, bj.z);
      float ry = fminf(bi.w, bj.w);
      float iw = fmaxf(rx - lx, 0.0f);
      float ih = fmaxf(ry - ly, 0.0f);
      float inter = iw * ih;
      float area_j = (bj.z - bj.x) * (bj.w - bj.y);
      float iou = inter / (area_i + area_j - inter);
      bool pred = (j > i) && (j < K) && (iou > 0.5f);
      word = __ballot(pred);
      any = any || (word != 0ull);
    }
    if (lane == 0) {
      if (act) mrow[w] = word;
      if (w == tc)      diag[(size_t)b * NB + i]  = word;
      else if (w == tc + 1) diag2[(size_t)b * NB + i] = word;   // 0 if !act
    }
  }
  if (lane == 0) anyf[wave] = any ? 1u : 0u;
  __syncthreads();
  if (threadIdx.x == 0) {
    u32 a = anyf[0] | anyf[1] | anyf[2] | anyf[3];
    rownz[(size_t)b * NB + i] = (unsigned char)(a ? 1 : 0);
  }
}

// ---------------------------------------------------------------------------
// Kernel 5: PAIRED chunked greedy scan + fused output (unchanged from r10).
// ---------------------------------------------------------------------------
#define SCAN_WAVES 8
#define MAXROWS 10

__device__ inline void resolve_diag(u64& rc, u64 dw) {
  u64 nzd = __ballot(dw != 0ull) & ~rc;
  while (nzd) {
    int tt = __builtin_ctzll(nzd);
    rc |= rdl64(dw, tt);
    nzd &= ~(1ull << tt) & ~rc;
  }
}

__global__ __launch_bounds__(512) void scan_kernel(const u64* __restrict__ mask,
                                                   const u64* __restrict__ diag,
                                                   const u64* __restrict__ diag2,
                                                   const unsigned char* __restrict__ rownz,
                                                   const u32* __restrict__ kcount,
                                                   const float4* __restrict__ sboxes,
                                                   const float* __restrict__ sprob,
                                                   float* __restrict__ out) {
  __shared__ u64 s_remv[WPR];               // finalized rc words (1 KB)
  __shared__ u64 s_slotE[2][SCAN_WAVES];    // posts of word 2t+2
  __shared__ u64 s_slotO[2][SCAN_WAVES];    // posts of word 2t+3
  __shared__ u64 s_kuA, s_kuB, s_nzwA, s_nzwB;
  const int b = blockIdx.x;
  const int tid = threadIdx.x;
  const int w = tid >> 6;                   // wave id 0..7
  const int l = tid & 63;
  const int K = (int)kcount[b];
  const u64* mb = mask + (size_t)b * NB * WPR;
  const u64* dg = diag + (size_t)b * NB;
  const u64* dg2 = diag2 + (size_t)b * NB;
  const unsigned char* nzb = rownz + (size_t)b * NB;
  const int NC = min(WPR, (K + 63) >> 6);
  const int NCL = min(NC, 64);
  const int NP = (NC + 1) >> 1;             // chunk pairs

  if (tid < 2 * SCAN_WAVES) { ((u64*)s_slotE)[tid] = 0; ((u64*)s_slotO)[tid] = 0; }

  u64 plo = 0, phi = 0;
  const bool okLo = (l < NCL);
  const bool okHi = (64 + l) < NC;
  u64 LA[MAXROWS], HA[MAXROWS], LB[MAXROWS], HB[MAXROWS];
  u64 bqA[MAXROWS], bqB[MAXROWS];
  u64 dwA = 0, dwB = 0, cw = 0;
  unsigned char nzcA = 0, nzcB = 0;

  if (w == 0 && NP > 0) {
    int rA = l, rB = 64 + l;
    dwA = (rA < K) ? dg[rA] : 0ull;
    dwB = (rB < K) ? dg[rB] : 0ull;
    cw  = (rA < K) ? dg2[rA] : 0ull;
    nzcA = (rA < K) ? nzb[rA] : (unsigned char)0;
    nzcB = (rB < K) ? nzb[rB] : (unsigned char)0;
    u64 a0 = __ballot(nzcA != 0), b0 = __ballot(nzcB != 0);
    if (l == 0) { s_nzwA = a0; s_nzwB = b0; }
  }
  __syncthreads();

  for (int t = 0; t < NP; ++t) {
    const int cA = 2 * t, cB = 2 * t + 1;
    const bool hasB = (cB < NC);
    // ---------------- phase 1 ----------------
    if (w == 0) {
      u64 dwA_n = 0, dwB_n = 0, cw_n = 0;
      unsigned char nzA_n = 0, nzB_n = 0;
      if (t + 1 < NP) {
        int rA = (t + 1) * 128 + l, rB = (t + 1) * 128 + 64 + l;
        dwA_n = (rA < K) ? dg[rA] : 0ull;
        dwB_n = (rB < K) ? dg[rB] : 0ull;
        cw_n  = (rA < K) ? dg2[rA] : 0ull;
        nzA_n = (rA < K) ? nzb[rA] : (unsigned char)0;
        nzB_n = (rB < K) ? nzb[rB] : (unsigned char)0;
      }
      int pr = (t + 1) & 1;
      u64 valA = s_slotE[pr][l & (SCAN_WAVES - 1)];
      u64 valB = s_slotO[pr][l & (SCAN_WAVES - 1)];
#pragma unroll
      for (int off = 1; off < SCAN_WAVES; off <<= 1) {
        valA |= shflxor64(valA, off);
        valB |= shflxor64(valB, off);
      }
      int loA = cA * 64;
      u64 tailA = (loA + 64 <= K) ? 0ull : ((~0ull) << (K - loA));
      u64 rcA = valA | tailA;
      u64 nzwA = __ballot(nzcA != 0);
      resolve_diag(rcA, dwA);
      u64 kuA = (~rcA) & nzwA;
      u64 m = ((~rcA >> l) & 1ull) ? cw : 0ull;
#pragma unroll
      for (int off = 32; off > 0; off >>= 1) m |= shflxor64(m, off);
      u64 rcB = ~0ull, kuB = 0;
      if (hasB) {
        int loB = cB * 64;
        u64 tailB = (loB + 64 <= K) ? 0ull : ((~0ull) << (K - loB));
        rcB = valB | tailB | m;
        u64 nzwB = __ballot(nzcB != 0);
        resolve_diag(rcB, dwB);
        kuB = (~rcB) & nzwB;
      }
      if (l == 0) {
        s_remv[cA] = rcA;
        if (hasB) s_remv[cB] = rcB;
        s_kuA = kuA; s_kuB = kuB;
      }
      dwA = dwA_n; dwB = dwB_n; cw = cw_n; nzcA = nzA_n; nzcB = nzB_n;
    } else {
      u64 kkA = (s_nzwA >> ((w - 1) * MAXROWS)) & ((1ull << MAXROWS) - 1ull);
      u64 kkB = (s_nzwB >> ((w - 1) * MAXROWS)) & ((1ull << MAXROWS) - 1ull);
#pragma unroll
      for (int q = 0; q < MAXROWS; ++q) {
        bool hA = (kkA != 0ull);
        int tA = hA ? __builtin_ctzll(kkA) : 0;
        if (hA) kkA &= kkA - 1;
        bqA[q] = hA ? (1ull << ((w - 1) * MAXROWS + tA)) : 0ull;
        LA[q] = 0; HA[q] = 0;
        if (hA) {
          const u64* rp = mb + (size_t)(cA * 64 + (w - 1) * MAXROWS + tA) * WPR;
          if (okLo) LA[q] = rp[l];
          if (okHi) HA[q] = rp[64 + l];
        }
        bool hB = (kkB != 0ull);
        int tB = hB ? __builtin_ctzll(kkB) : 0;
        if (hB) kkB &= kkB - 1;
        bqB[q] = hB ? (1ull << ((w - 1) * MAXROWS + tB)) : 0ull;
        LB[q] = 0; HB[q] = 0;
        if (hB) {
          const u64* rp = mb + (size_t)(cB * 64 + (w - 1) * MAXROWS + tB) * WPR;
          if (okLo) LB[q] = rp[l];
          if (okHi) HB[q] = rp[64 + l];
        }
      }
    }
    __syncthreads();                     // barrier A

    // ---------------- phase 2 (register/LDS only) ----------------
    if (w == 0) {
      u64 a1 = __ballot(nzcA != 0), b1 = __ballot(nzcB != 0);
      if (l == 0) { s_nzwA = a1; s_nzwB = b1; }
    } else {
      u64 kuA = s_kuA, kuB = s_kuB;
#pragma unroll
      for (int q = 0; q < MAXROWS; ++q) {
        if (kuA & bqA[q]) { plo |= LA[q]; phi |= HA[q]; }
        if (kuB & bqB[q]) { plo |= LB[q]; phi |= HB[q]; }
      }
      int wE = cA + 2, wO = cA + 3;
      u64 vE = (wE < 64) ? plo : phi;
      if (l == (wE & 63)) s_slotE[t & 1][w] = vE;
      u64 vO = (wO < 64) ? plo : phi;
      if (l == (wO & 63)) s_slotO[t & 1][w] = vO;
    }
    __syncthreads();                     // barrier B
  }

  // ---------------- fused output ----------------
  const float4* sbx = sboxes + (size_t)b * NB;
  const float* spb = sprob + (size_t)b * NB;
  for (int p = tid; p < NB; p += 512) {
    bool kp = false;
    if (p < K) {
      u64 wv = s_remv[p >> 6];
      kp = !((wv >> (p & 63)) & 1ull);
    }
    float4 bv = sbx[p];
    if (!kp) { bv.x = 0.0f; bv.y = 0.0f; bv.z = 0.0f; bv.w = 0.0f; }
    ((float4*)out)[(size_t)b * NB + p] = bv;
    out[(size_t)BIMG * NB * 4 + (size_t)b * NB + p] = kp ? spb[p] : 0.0f;
    out[(size_t)BIMG * NB * 5 + (size_t)b * NB + p] = kp ? 1.0f : 0.0f;
  }
}

// ---------------------------------------------------------------------------
// Fallback NMS kernel (used only if workspace is too small): consumes the
// already-sorted sboxes/sprob from sort_kernel.
// ---------------------------------------------------------------------------
__global__ __launch_bounds__(1024) void nms_kernel(const float4* __restrict__ sboxes,
                                                   const float* __restrict__ sprob,
                                                   const u32* __restrict__ kcount,
                                                   float* __restrict__ out) {
  __shared__ float4 sb[NB];
  __shared__ unsigned char flag[NB];
  const int b = blockIdx.x;
  const int t = threadIdx.x;
  const int K = (int)kcount[b];

  for (int p = t; p < NB; p += 1024) {
    sb[p] = sboxes[(size_t)b * NB + p];
    flag[p] = (p < K) ? (unsigned char)0 : (unsigned char)1;
  }
  __syncthreads();

  for (int i = 0; i < K; ++i) {
    if (flag[i]) continue;
    float4 bi = sb[i];
    float area_i = (bi.z - bi.x) * (bi.w - bi.y);
    for (int j = i + 1 + t; j < K; j += 1024) {
      float4 bj = sb[j];
      float lx = fmaxf(bi.x, bj.x);
      float ly = fmaxf(bi.y, bj.y);
      float rx = fminf(bi.z, bj.z);
      float ry = fminf(bi.w, bj.w);
      float iw = fmaxf(rx - lx, 0.0f);
      float ih = fmaxf(ry - ly, 0.0f);
      float inter = iw * ih;
      float area_j = (bj.z - bj.x) * (bj.w - bj.y);
      float iou = inter / (area_i + area_j - inter);
      if (iou > 0.5f) flag[j] = (unsigned char)1;
    }
    __syncthreads();
  }

  float4* oboxes = (float4*)(out) + (size_t)b * NB;
  float* oscores = out + (size_t)BIMG * NB * 4 + (size_t)b * NB;
  float* okeep   = out + (size_t)BIMG * NB * 5 + (size_t)b * NB;
  for (int p = t; p < NB; p += 1024) {
    bool kp = (p < K) && (flag[p] == 0);
    float4 bv = sb[p];
    if (!kp) { bv.x = 0.0f; bv.y = 0.0f; bv.z = 0.0f; bv.w = 0.0f; }
    oboxes[p] = bv;
    oscores[p] = kp ? sprob[(size_t)b * NB + p] : 0.0f;
    okeep[p] = kp ? 1.0f : 0.0f;
  }
}

// ---------------------------------------------------------------------------
extern "C" void kernel_launch(void* const* d_in, const int* in_sizes, int n_in,
                              void* d_out, int out_size, void* d_ws, size_t ws_size,
                              hipStream_t stream) {
  const float* offsets = (const float*)d_in[0];   // [B,N,4] f32
  const float* labels  = (const float*)d_in[1];   // [B,N,1] f32
  const float* anchors = (const float*)d_in[2];   // [N,4]   f32
  float* out = (float*)d_out;

  char* ws = (char*)d_ws;
  u32*    kcount = (u32*)(ws + WS_KCOUNT);
  float4* boxes  = (float4*)(ws + WS_BOXES);
  float*  prob   = (float*)(ws + WS_PROB);
  float4* sboxes = (float4*)(ws + WS_SBOXES);
  float*  sprob  = (float*)(ws + WS_SPROB);

  sort_kernel<<<BIMG, 1024, 0, stream>>>(offsets, labels, anchors,
                                         boxes, prob, sboxes, sprob, kcount);

  if (ws_size >= WS_NEEDED) {
    u64*    mask   = (u64*)(ws + WS_MASK);
    unsigned char* rownz = (unsigned char*)(ws + WS_ROWNZ);
    u64*    diag   = (u64*)(ws + WS_DIAG);
    u64*    diag2  = (u64*)(ws + WS_DIAG2);

    mask_kernel<<<dim3(NB, BIMG), 256, 0, stream>>>(sboxes, kcount, mask, rownz,
                                                    diag, diag2);

    scan_kernel<<<BIMG, 512, 0, stream>>>(mask, diag, diag2, rownz, kcount,
                                          sboxes, sprob, out);
  } else {
    nms_kernel<<<BIMG, 1024, 0, stream>>>(sboxes, sprob, kcount, out);
  }
}